// Round 10
// baseline (7227.734 us; speedup 1.0000x reference)
//
#include <hip/hip_runtime.h>

#define BLOCK 512
#define GRID  256          // = #CUs; 152KB LDS => 1 block/CU => plain launch co-resident
#define PPT   4            // GRID*BLOCK*PPT = 524288 >= N
#define V     8            // DIMS/4 float4s per row
#define V3    3            // float4s of point 3 parked in LDS (rest in AGPRs)
#define DIMS  32
#define SLOTS_PER_THREAD (GRID / 64)   // wave-0 gather: 4 slots per lane

// ---- explicit AGPR residency (round-4 win: FETCH 30.4GB -> 1.9GB) -----------
// The allocator splits the unified file 128 arch + 128 acc and spills overflow
// ARRAYS to memory scratch instead of the idle AGPR half. These helpers pin
// values into AGPRs. volatile: LICM must not hoist the reads back out of the
// step loop (that would re-inflate arch pressure and re-spill).
// Rounds 5/6 lesson: the step loop is at a regalloc knife's edge — NO wrapper
// functions, NO templates, NO in-loop uniform branches.
// Round 8 lesson: NEVER issue a load whose result is unconsumed — a dead asm
// load dest is reused by regalloc and the async retire clobbers live registers.
__device__ __forceinline__ float to_agpr(float v) {
    float r;
    asm volatile("v_accvgpr_write_b32 %0, %1" : "=a"(r) : "v"(v));
    return r;
}
__device__ __forceinline__ float from_agpr(float a) {
    float r;
    asm volatile("v_accvgpr_read_b32 %0, %1" : "=v"(r) : "a"(a));
    return r;
}

// Monotone map: smaller float -> smaller u32 key (ties broken by index).
__device__ __forceinline__ unsigned pack_f32(float v) {
    unsigned u = __float_as_uint(v);
    return (u & 0x80000000u) ? ~u : (u | 0x80000000u);
}

__device__ __forceinline__ unsigned long long pack_min(float v, unsigned idx) {
    return ((unsigned long long)pack_f32(v) << 32) | (unsigned long long)idx;
}

__device__ __forceinline__ unsigned long long shfl_down_u64(unsigned long long v, int off) {
    unsigned lo = (unsigned)(v & 0xffffffffu);
    unsigned hi = (unsigned)(v >> 32);
    lo = __shfl_down(lo, off, 64);
    hi = __shfl_down(hi, off, 64);
    return ((unsigned long long)hi << 32) | (unsigned long long)lo;
}

// Butterfly: ALL 64 lanes end with the wave-wide min.
__device__ __forceinline__ unsigned long long shfl_xor_u64(unsigned long long v, int mask) {
    unsigned lo = (unsigned)(v & 0xffffffffu);
    unsigned hi = (unsigned)(v >> 32);
    lo = __shfl_xor(lo, mask, 64);
    hi = __shfl_xor(hi, mask, 64);
    return ((unsigned long long)hi << 32) | (unsigned long long)lo;
}

// Full-block min reduction (init phase only); every thread returns the block min.
__device__ __forceinline__ unsigned long long block_min_reduce(unsigned long long v,
                                                              unsigned long long* scratch) {
    #pragma unroll
    for (int off = 32; off >= 1; off >>= 1) {
        unsigned long long o = shfl_down_u64(v, off);
        v = (o < v) ? o : v;
    }
    const int wave = threadIdx.x >> 6;
    const int lane = threadIdx.x & 63;
    if (lane == 0) scratch[wave] = v;
    __syncthreads();
    unsigned long long r = scratch[0];
    #pragma unroll
    for (int i = 1; i < (BLOCK / 64); ++i) {
        unsigned long long o = scratch[i];
        r = (o < r) ? o : r;
    }
    __syncthreads();  // scratch safe for reuse
    return r;
}

// Post this block's min for step t. Slot key: [val:32 | step:12 | idx:20].
__device__ __forceinline__ void post_slot(unsigned long long* __restrict__ slots,
                                          unsigned long long blockmin, int t) {
    if (threadIdx.x == 0) {
        const unsigned long long val = blockmin >> 32;
        const unsigned long long idx = blockmin & 0xFFFFFull;   // all idx < 2^20
        const unsigned long long key =
            (val << 32) | ((unsigned long long)((unsigned)t & 0xFFFu) << 20) | idx;
        __hip_atomic_store(&slots[(size_t)(t & 1) * GRID + blockIdx.x], key,
                           __ATOMIC_RELAXED, __HIP_MEMORY_SCOPE_AGENT);
    }
}

// One poll round: issue this lane's 4 slot loads (relaxed, agent scope).
__device__ __forceinline__ void poll_issue(const unsigned long long* __restrict__ slotp,
                                           unsigned long long* k) {
    #pragma unroll
    for (int s = 0; s < SLOTS_PER_THREAD; ++s)
        k[s] = __hip_atomic_load(&slotp[threadIdx.x + 64 * s],
                                 __ATOMIC_RELAXED, __HIP_MEMORY_SCOPE_AGENT);
}

__device__ __forceinline__ bool poll_ok(const unsigned long long* k, unsigned want) {
    bool ok = true;
    #pragma unroll
    for (int s = 0; s < SLOTS_PER_THREAD; ++s)
        ok &= (((unsigned)(k[s] >> 20) & 0xFFFu) == want);
    return ok;
}

// Fused gather + pivot stage: wave0 polls all GRID slots for step t, butterfly
// gives the grid min to all 64 lanes, lanes<16 immediately fetch the pivot row
// (L3-warm: x/score_p fit in the 256MB IF since init), lane 0 publishes gmin.
// ONE barrier releases the block.
//
// Round-10: SOFTWARE-PIPELINED poll. Rounds were serialized (issue -> full IF
// RTT -> check -> issue...), so detection lag after the last post was up to
// 2 RTT. Double-buffering (issue round i+1 before checking round i) makes
// rounds complete back-to-back at RTT spacing: lag ~= 1 RTT. The in-flight
// speculative round at exit is DISCARDED — benign (relaxed loads, values
// unused; every load is consumed by the check, round-8 rule respected).
//
// Hazard audit (unchanged from r7/r9): thread0's scratch-read + post(t)
// happens-before any block's poll(t) success, which happens-before wave0's
// arrival here at t+1, which happens-before the next xi4/si4/gmin_sh writes.
// 2-buffer slot parity: a block posts t+2 only after gathering all t+1 posts,
// whose authors had finished reading every step-t slot.
__device__ __forceinline__ void gather_stage(
    const unsigned long long* __restrict__ slotp, int t,
    unsigned long long* gmin_sh,
    const float4* __restrict__ X4, const float4* __restrict__ S4,
    float4* xi4, float4* si4)
{
    if (threadIdx.x < 64) {
        const unsigned want = (unsigned)t & 0xFFFu;
        unsigned long long ka[SLOTS_PER_THREAD], kb[SLOTS_PER_THREAD];
        unsigned long long use[SLOTS_PER_THREAD];
        poll_issue(slotp, ka);
        for (;;) {
            poll_issue(slotp, kb);            // in flight while ka is checked
            if (poll_ok(ka, want)) {
                #pragma unroll
                for (int s = 0; s < SLOTS_PER_THREAD; ++s) use[s] = ka[s];
                break;
            }
            poll_issue(slotp, ka);            // in flight while kb is checked
            if (poll_ok(kb, want)) {
                #pragma unroll
                for (int s = 0; s < SLOTS_PER_THREAD; ++s) use[s] = kb[s];
                break;
            }
        }
        unsigned long long lb = use[0];
        #pragma unroll
        for (int s = 1; s < SLOTS_PER_THREAD; ++s)
            if (use[s] < lb) lb = use[s];
        #pragma unroll
        for (int mask = 32; mask >= 1; mask >>= 1) {
            unsigned long long o = shfl_xor_u64(lb, mask);
            lb = (o < lb) ? o : lb;
        }
        const int idx = (int)(lb & 0xFFFFFull);
        if (threadIdx.x < 16) {
            const size_t pb = (size_t)idx * V;
            if (threadIdx.x < 8) xi4[threadIdx.x] = X4[pb + threadIdx.x];
            else                 si4[threadIdx.x - 8] = S4[pb + (threadIdx.x - 8)];
        }
        if (threadIdx.x == 0) *gmin_sh = lb;
    }
    __syncthreads();
}

// waves_per_eu(2,2): 2 waves/SIMD (the LDS cap enforces 1 block/CU anyway)
// => 256-register TOTAL budget per wave (arch + acc halves of the unified file).
__global__
__attribute__((amdgpu_flat_work_group_size(512, 512),
               amdgpu_waves_per_eu(2, 2)))
void stein_thin_persist(
    const float* __restrict__ x, const float* __restrict__ log_p,
    const float* __restrict__ score_p, const float* __restrict__ laplace,
    const float* __restrict__ ls_ptr, int* __restrict__ out,
    unsigned long long* __restrict__ slots, int N, int m)
{
    const int tid = blockIdx.x * BLOCK + threadIdx.x;
    const int T = GRID * BLOCK;          // 131072
    const int lane = threadIdx.x & 63;
    const int wave = threadIdx.x >> 6;

    const float ell = ls_ptr[0];
    const float ell2 = ell * ell;
    const float w = 1.0f / (float)m;                 // weight_entropy = 1/m
    const float dim_over_ell2 = (float)DIMS / ell2;
    // Divide->multiply: for the unit lengthscale (ell2 == 1.0f) inv_ell2 == 1.0f
    // and x*1.0f == x/1.0f bit-exactly (rounds 7/9 verified).
    const float inv_ell2 = 1.0f / ell2;
    const float inv2 = inv_ell2 * inv_ell2;

    const float4* __restrict__ X4 = (const float4*)x;
    const float4* __restrict__ S4 = (const float4*)score_p;

    // LDS: tier A 128 KB + tier B 24 KB + pivot/reduce ~0.5 KB (conflict-free
    // transposed layout, SQ_LDS_BANK_CONFLICT = 0 verified).
    __shared__ float4 s_ldsT[V][2 * BLOCK];   // S-rows of points 0,1 (128 KB)
    __shared__ float4 s_lds3[V3][BLOCK];      // first 3 float4s of point 3 (24 KB)
    __shared__ float4 xi4[V];
    __shared__ float4 si4[V];
    __shared__ unsigned long long gmin_sh;
    __shared__ unsigned long long red_scratch[BLOCK / 64];

    // -------- persistent per-thread state ------------------------------------
    // arch VGPRs (<=128): xr0,xr1 (64) + acc (16) + objr/lpr (8) + workspace
    // AGPRs (116/128):    ax2,ax3 (x-rows of points 2,3) + as2 + as3 tail
    // LDS: S-rows of points 0,1 + first 3 float4s of point 3
    // => step loop has ZERO global data traffic and ZERO scratch traffic.
    float4 xr0[V];
    float4 xr1[V];
    float ax2[DIMS], ax3[DIMS];          // AGPR-resident (all indices constant)
    float as2[DIMS], as3[(V - V3) * 4];  // AGPR-resident
    float objr[PPT], lpr[PPT];

    {
        unsigned long long lbest = ~0ULL;
        #pragma unroll
        for (int p = 0; p < PPT; ++p) {
            const int j = tid + p * T;
            const bool act = (j < N);
            const int jc = act ? j : (N - 1);        // clamp: loads stay in-bounds
            const size_t base = (size_t)jc * V;
            float ss = 0.0f;
            #pragma unroll
            for (int v = 0; v < V; ++v) {
                const float4 s = S4[base + v];
                if (p < 2) s_ldsT[v][p * BLOCK + threadIdx.x] = s;
                if (p == 2) {
                    as2[4 * v + 0] = to_agpr(s.x); as2[4 * v + 1] = to_agpr(s.y);
                    as2[4 * v + 2] = to_agpr(s.z); as2[4 * v + 3] = to_agpr(s.w);
                }
                if (p == 3) {
                    if (v < V3) s_lds3[v][threadIdx.x] = s;
                    else {
                        const int b = (v - V3) * 4;
                        as3[b + 0] = to_agpr(s.x); as3[b + 1] = to_agpr(s.y);
                        as3[b + 2] = to_agpr(s.z); as3[b + 3] = to_agpr(s.w);
                    }
                }
                const float4 xx = X4[base + v];
                if (p == 0) xr0[v] = xx;
                else if (p == 1) xr1[v] = xx;
                else if (p == 2) {
                    ax2[4 * v + 0] = to_agpr(xx.x); ax2[4 * v + 1] = to_agpr(xx.y);
                    ax2[4 * v + 2] = to_agpr(xx.z); ax2[4 * v + 3] = to_agpr(xx.w);
                } else {
                    ax3[4 * v + 0] = to_agpr(xx.x); ax3[4 * v + 1] = to_agpr(xx.y);
                    ax3[4 * v + 2] = to_agpr(xx.z); ax3[4 * v + 3] = to_agpr(xx.w);
                }
                ss += s.x * s.x; ss += s.y * s.y; ss += s.z * s.z; ss += s.w * s.w;
            }
            lpr[p] = log_p[jc];
            // identical source shape to the previously verified kernels:
            float o = ((dim_over_ell2 + ss) + laplace[jc]) - w * log_p[jc];
            if (!act) o = __int_as_float(0x7F800000);   // +inf: never selected
            objr[p] = o;
            const unsigned long long pk = pack_min(o, (unsigned)j);
            if (pk < lbest) lbest = pk;
        }
        post_slot(slots, block_min_reduce(lbest, red_scratch), 0);
    }
    __syncthreads();   // LDS tiers fully populated before the step loop

    // -------- steps 1..m-1: 3 barriers per step ------------------------------
    // gather_stage (1 barrier) -> compute -> lane0s->scratch (1 barrier) ->
    // thread0 block-min + post. Hazard audit in gather_stage's comment.
    for (int t = 1; t < m; ++t) {
        gather_stage(slots + (size_t)((t - 1) & 1) * GRID, t - 1, &gmin_sh,
                     X4, S4, xi4, si4);
        if (blockIdx.x == 0 && threadIdx.x == 0)
            out[t - 1] = (int)(gmin_sh & 0xFFFFFull);

        // OUTER-v / INNER-p (round-9 win): pivot xi4[v]/si4[v] read ONCE per v
        // — removed 48 broadcast ds_read_b128/thread/step from the shared LDS
        // pipe (−4.6us/step). Per-accumulator FP order (v ascending, x/y/z/w)
        // unchanged => bit-identical results. 16 accumulators, all
        // compile-time-indexed (SROA -> registers).
        float r2a[PPT], c1a[PPT], c2a[PPT], dssa[PPT];
        #pragma unroll
        for (int p = 0; p < PPT; ++p) {
            r2a[p] = 0.0f; c1a[p] = 0.0f; c2a[p] = 0.0f; dssa[p] = 0.0f;
        }

        #pragma unroll
        for (int v = 0; v < V; ++v) {
            const float4 xp = xi4[v];
            const float4 sp = si4[v];
            #pragma unroll
            for (int p = 0; p < PPT; ++p) {
                float4 xv, sv;
                if (p == 0)      { xv = xr0[v]; sv = s_ldsT[v][threadIdx.x]; }
                else if (p == 1) { xv = xr1[v]; sv = s_ldsT[v][BLOCK + threadIdx.x]; }
                else if (p == 2) {
                    xv.x = from_agpr(ax2[4 * v + 0]); xv.y = from_agpr(ax2[4 * v + 1]);
                    xv.z = from_agpr(ax2[4 * v + 2]); xv.w = from_agpr(ax2[4 * v + 3]);
                    sv.x = from_agpr(as2[4 * v + 0]); sv.y = from_agpr(as2[4 * v + 1]);
                    sv.z = from_agpr(as2[4 * v + 2]); sv.w = from_agpr(as2[4 * v + 3]);
                } else {
                    xv.x = from_agpr(ax3[4 * v + 0]); xv.y = from_agpr(ax3[4 * v + 1]);
                    xv.z = from_agpr(ax3[4 * v + 2]); xv.w = from_agpr(ax3[4 * v + 3]);
                    if (v < V3) sv = s_lds3[v][threadIdx.x];
                    else {
                        const int b = (v - V3) * 4;
                        sv.x = from_agpr(as3[b + 0]); sv.y = from_agpr(as3[b + 1]);
                        sv.z = from_agpr(as3[b + 2]); sv.w = from_agpr(as3[b + 3]);
                    }
                }
                float d;
                d = xp.x - xv.x; r2a[p] += d * d; c1a[p] += d * sp.x; c2a[p] += sv.x * d; dssa[p] += sv.x * sp.x;
                d = xp.y - xv.y; r2a[p] += d * d; c1a[p] += d * sp.y; c2a[p] += sv.y * d; dssa[p] += sv.y * sp.y;
                d = xp.z - xv.z; r2a[p] += d * d; c1a[p] += d * sp.z; c2a[p] += sv.z * d; dssa[p] += sv.z * sp.z;
                d = xp.w - xv.w; r2a[p] += d * d; c1a[p] += d * sp.w; c2a[p] += sv.w * d; dssa[p] += sv.w * sp.w;
            }
        }

        unsigned long long lbest = ~0ULL;
        #pragma unroll
        for (int p = 0; p < PPT; ++p) {
            const float r2 = r2a[p];
            const float q   = 1.0f + r2 * inv_ell2;
            const float qi  = 1.0f / q;
            const float sq  = sqrtf(qi);        // q^-0.5
            const float g   = qi * sq;          // q^-1.5
            const float q25 = qi * qi * sq;     // q^-2.5
            const float cross = (c1a[p] - c2a[p]) * inv_ell2;
            const float k = ((dim_over_ell2 * g - 3.0f * r2 * inv2 * q25)
                             + cross * g) + dssa[p] * sq;
            // +inf rows stay +inf (their loads were clamped to a real row => k finite)
            const float o = objr[p] + (2.0f * k - w * lpr[p]);
            objr[p] = o;
            const unsigned long long pk = pack_min(o, (unsigned)(tid + p * T));
            if (pk < lbest) lbest = pk;
        }

        #pragma unroll
        for (int off = 32; off >= 1; off >>= 1) {
            unsigned long long o = shfl_down_u64(lbest, off);
            lbest = (o < lbest) ? o : lbest;
        }
        if (lane == 0) red_scratch[wave] = lbest;
        __syncthreads();
        if (threadIdx.x == 0) {
            unsigned long long r = red_scratch[0];
            #pragma unroll
            for (int i = 1; i < (BLOCK / 64); ++i) {
                unsigned long long o = red_scratch[i];
                r = (o < r) ? o : r;
            }
            post_slot(slots, r, t);
        }
    }

    // -------- final argmin -> out[m-1] ----------------------------------------
    {
        gather_stage(slots + (size_t)((m - 1) & 1) * GRID, m - 1, &gmin_sh,
                     X4, S4, xi4, si4);
        if (blockIdx.x == 0 && threadIdx.x == 0)
            out[m - 1] = (int)(gmin_sh & 0xFFFFFull);
    }
}

extern "C" void kernel_launch(void* const* d_in, const int* in_sizes, int n_in,
                              void* d_out, int out_size, void* d_ws, size_t ws_size,
                              hipStream_t stream) {
    const float* x        = (const float*)d_in[0];
    const float* log_p    = (const float*)d_in[1];
    const float* score_p  = (const float*)d_in[2];
    const float* laplace  = (const float*)d_in[3];
    const float* ls_ptr   = (const float*)d_in[4];

    int* out = (int*)d_out;
    int N = in_sizes[1];            // log_p has N elements
    int m = out_size;

    unsigned long long* slots = (unsigned long long*)d_ws;  // 2*GRID u64 = 4 KB

    // Single deterministic path: plain launch, identical on every call
    // (correctness call, graph capture, tripwire). 152 KB LDS => exactly
    // 1 block/CU => 256 blocks on 256 CUs are structurally co-resident.
    stein_thin_persist<<<dim3(GRID), dim3(BLOCK), 0, stream>>>(
        x, log_p, score_p, laplace, ls_ptr, out, slots, N, m);
}

// Round 11
// 6045.409 us; speedup vs baseline: 1.1956x; 1.1956x over previous
//
#include <hip/hip_runtime.h>

#define BLOCK 512
#define GRID  256          // = #CUs; 152KB LDS => 1 block/CU => plain launch co-resident
#define PPT   4            // GRID*BLOCK*PPT = 524288 >= N
#define V     8            // DIMS/4 float4s per row
#define V3    3            // float4s of point 3 parked in LDS (rest in AGPRs)
#define DIMS  32
#define SLOTS_PER_THREAD (GRID / 64)   // wave-0 gather: 4 slots per lane

// ---- explicit AGPR residency (round-4 win: FETCH 30.4GB -> 1.9GB) -----------
// The allocator splits the unified file 128 arch + 128 acc and spills overflow
// ARRAYS to memory scratch instead of the idle AGPR half. These helpers pin
// values into AGPRs. volatile: LICM must not hoist the reads back out of the
// step loop (that would re-inflate arch pressure and re-spill).
// Rounds 5/6 lesson: the step loop is at a regalloc knife's edge — NO wrapper
// functions, NO templates, NO in-loop uniform branches.
// Round 8 lesson: NEVER issue a load whose result is unconsumed — a dead asm
// load dest is reused by regalloc and the async retire clobbers live registers.
// Round 10 lesson: poll double-buffering is neutral (loads already pipeline
// within a round); keep the simple poll.
__device__ __forceinline__ float to_agpr(float v) {
    float r;
    asm volatile("v_accvgpr_write_b32 %0, %1" : "=a"(r) : "v"(v));
    return r;
}
__device__ __forceinline__ float from_agpr(float a) {
    float r;
    asm volatile("v_accvgpr_read_b32 %0, %1" : "=v"(r) : "a"(a));
    return r;
}

// Monotone map: smaller float -> smaller u32 key (ties broken by index).
__device__ __forceinline__ unsigned pack_f32(float v) {
    unsigned u = __float_as_uint(v);
    return (u & 0x80000000u) ? ~u : (u | 0x80000000u);
}

__device__ __forceinline__ unsigned long long pack_min(float v, unsigned idx) {
    return ((unsigned long long)pack_f32(v) << 32) | (unsigned long long)idx;
}

__device__ __forceinline__ unsigned long long shfl_down_u64(unsigned long long v, int off) {
    unsigned lo = (unsigned)(v & 0xffffffffu);
    unsigned hi = (unsigned)(v >> 32);
    lo = __shfl_down(lo, off, 64);
    hi = __shfl_down(hi, off, 64);
    return ((unsigned long long)hi << 32) | (unsigned long long)lo;
}

// Butterfly: ALL 64 lanes end with the wave-wide min.
__device__ __forceinline__ unsigned long long shfl_xor_u64(unsigned long long v, int mask) {
    unsigned lo = (unsigned)(v & 0xffffffffu);
    unsigned hi = (unsigned)(v >> 32);
    lo = __shfl_xor(lo, mask, 64);
    hi = __shfl_xor(hi, mask, 64);
    return ((unsigned long long)hi << 32) | (unsigned long long)lo;
}

// Full-block min reduction (init phase only); every thread returns the block min.
__device__ __forceinline__ unsigned long long block_min_reduce(unsigned long long v,
                                                              unsigned long long* scratch) {
    #pragma unroll
    for (int off = 32; off >= 1; off >>= 1) {
        unsigned long long o = shfl_down_u64(v, off);
        v = (o < v) ? o : v;
    }
    const int wave = threadIdx.x >> 6;
    const int lane = threadIdx.x & 63;
    if (lane == 0) scratch[wave] = v;
    __syncthreads();
    unsigned long long r = scratch[0];
    #pragma unroll
    for (int i = 1; i < (BLOCK / 64); ++i) {
        unsigned long long o = scratch[i];
        r = (o < r) ? o : r;
    }
    __syncthreads();  // scratch safe for reuse
    return r;
}

// Post this block's min for step t. Slot key: [val:32 | step:12 | idx:20].
__device__ __forceinline__ void post_slot(unsigned long long* __restrict__ slots,
                                          unsigned long long blockmin, int t) {
    if (threadIdx.x == 0) {
        const unsigned long long val = blockmin >> 32;
        const unsigned long long idx = blockmin & 0xFFFFFull;   // all idx < 2^20
        const unsigned long long key =
            (val << 32) | ((unsigned long long)((unsigned)t & 0xFFFu) << 20) | idx;
        __hip_atomic_store(&slots[(size_t)(t & 1) * GRID + blockIdx.x], key,
                           __ATOMIC_RELAXED, __HIP_MEMORY_SCOPE_AGENT);
    }
}

// Gather: wave0 polls all GRID slots for step t (simple serialized rounds —
// r10 showed pipelining is neutral), butterfly gives the grid min to all 64
// lanes, lane 0 publishes gmin_sh. ONE barrier releases the block.
//
// Round-11 change: NO pivot staging here. Previously 16 lanes fetched the
// 512B pivot row global->LDS with a vmcnt drain BEFORE the release barrier —
// a fully serial L2/L3 round-trip on every block's critical path every step.
// Now each thread reads the pivot row directly from global in the compute
// loop: first touch per CU misses once (latency overlapped with the unrolled
// loop's batched issue + the co-resident wave), the rest are L1-broadcast
// hits. x/score_p are never written => values identical, FP order identical.
//
// Hazard audit (simplified — no xi4/si4 buffers anymore): thread0's
// scratch-read + post(t) happens-before any block's poll(t) success, which
// happens-before wave0's arrival at this barrier for t+1. gmin_sh write (t+1)
// is separated from all step-t readers by this barrier. 2-buffer slot parity:
// a block posts t+2 only after gathering all t+1 posts, whose authors had
// finished reading every step-t slot.
__device__ __forceinline__ void gather_min(
    const unsigned long long* __restrict__ slotp, int t,
    unsigned long long* gmin_sh)
{
    if (threadIdx.x < 64) {
        const unsigned want = (unsigned)t & 0xFFFu;
        unsigned long long k[SLOTS_PER_THREAD];
        for (;;) {
            #pragma unroll
            for (int s = 0; s < SLOTS_PER_THREAD; ++s)
                k[s] = __hip_atomic_load(&slotp[threadIdx.x + 64 * s],
                                         __ATOMIC_RELAXED, __HIP_MEMORY_SCOPE_AGENT);
            bool ok = true;
            #pragma unroll
            for (int s = 0; s < SLOTS_PER_THREAD; ++s)
                ok &= (((unsigned)(k[s] >> 20) & 0xFFFu) == want);
            if (ok) break;
        }
        unsigned long long lb = k[0];
        #pragma unroll
        for (int s = 1; s < SLOTS_PER_THREAD; ++s)
            if (k[s] < lb) lb = k[s];
        #pragma unroll
        for (int mask = 32; mask >= 1; mask >>= 1) {
            unsigned long long o = shfl_xor_u64(lb, mask);
            lb = (o < lb) ? o : lb;
        }
        if (threadIdx.x == 0) *gmin_sh = lb;
    }
    __syncthreads();
}

// waves_per_eu(2,2): 2 waves/SIMD (the LDS cap enforces 1 block/CU anyway)
// => 256-register TOTAL budget per wave (arch + acc halves of the unified file).
__global__
__attribute__((amdgpu_flat_work_group_size(512, 512),
               amdgpu_waves_per_eu(2, 2)))
void stein_thin_persist(
    const float* __restrict__ x, const float* __restrict__ log_p,
    const float* __restrict__ score_p, const float* __restrict__ laplace,
    const float* __restrict__ ls_ptr, int* __restrict__ out,
    unsigned long long* __restrict__ slots, int N, int m)
{
    const int tid = blockIdx.x * BLOCK + threadIdx.x;
    const int T = GRID * BLOCK;          // 131072
    const int lane = threadIdx.x & 63;
    const int wave = threadIdx.x >> 6;

    const float ell = ls_ptr[0];
    const float ell2 = ell * ell;
    const float w = 1.0f / (float)m;                 // weight_entropy = 1/m
    const float dim_over_ell2 = (float)DIMS / ell2;
    // Divide->multiply: for the unit lengthscale (ell2 == 1.0f) inv_ell2 == 1.0f
    // and x*1.0f == x/1.0f bit-exactly (rounds 7/9 verified).
    const float inv_ell2 = 1.0f / ell2;
    const float inv2 = inv_ell2 * inv_ell2;

    const float4* __restrict__ X4 = (const float4*)x;
    const float4* __restrict__ S4 = (const float4*)score_p;

    // LDS: tier A 128 KB + tier B 24 KB + reduce scratch (conflict-free
    // transposed layout, SQ_LDS_BANK_CONFLICT = 0 verified).
    __shared__ float4 s_ldsT[V][2 * BLOCK];   // S-rows of points 0,1 (128 KB)
    __shared__ float4 s_lds3[V3][BLOCK];      // first 3 float4s of point 3 (24 KB)
    __shared__ unsigned long long gmin_sh;
    __shared__ unsigned long long red_scratch[BLOCK / 64];

    // -------- persistent per-thread state ------------------------------------
    // arch VGPRs (<=128): xr0,xr1 (64) + acc (16) + objr/lpr (8) + workspace
    // AGPRs (116/128):    ax2,ax3 (x-rows of points 2,3) + as2 + as3 tail
    // LDS: S-rows of points 0,1 + first 3 float4s of point 3
    // => step loop has ZERO global data traffic (except the shared 512B pivot
    // row, L1-broadcast) and ZERO scratch traffic.
    float4 xr0[V];
    float4 xr1[V];
    float ax2[DIMS], ax3[DIMS];          // AGPR-resident (all indices constant)
    float as2[DIMS], as3[(V - V3) * 4];  // AGPR-resident
    float objr[PPT], lpr[PPT];

    {
        unsigned long long lbest = ~0ULL;
        #pragma unroll
        for (int p = 0; p < PPT; ++p) {
            const int j = tid + p * T;
            const bool act = (j < N);
            const int jc = act ? j : (N - 1);        // clamp: loads stay in-bounds
            const size_t base = (size_t)jc * V;
            float ss = 0.0f;
            #pragma unroll
            for (int v = 0; v < V; ++v) {
                const float4 s = S4[base + v];
                if (p < 2) s_ldsT[v][p * BLOCK + threadIdx.x] = s;
                if (p == 2) {
                    as2[4 * v + 0] = to_agpr(s.x); as2[4 * v + 1] = to_agpr(s.y);
                    as2[4 * v + 2] = to_agpr(s.z); as2[4 * v + 3] = to_agpr(s.w);
                }
                if (p == 3) {
                    if (v < V3) s_lds3[v][threadIdx.x] = s;
                    else {
                        const int b = (v - V3) * 4;
                        as3[b + 0] = to_agpr(s.x); as3[b + 1] = to_agpr(s.y);
                        as3[b + 2] = to_agpr(s.z); as3[b + 3] = to_agpr(s.w);
                    }
                }
                const float4 xx = X4[base + v];
                if (p == 0) xr0[v] = xx;
                else if (p == 1) xr1[v] = xx;
                else if (p == 2) {
                    ax2[4 * v + 0] = to_agpr(xx.x); ax2[4 * v + 1] = to_agpr(xx.y);
                    ax2[4 * v + 2] = to_agpr(xx.z); ax2[4 * v + 3] = to_agpr(xx.w);
                } else {
                    ax3[4 * v + 0] = to_agpr(xx.x); ax3[4 * v + 1] = to_agpr(xx.y);
                    ax3[4 * v + 2] = to_agpr(xx.z); ax3[4 * v + 3] = to_agpr(xx.w);
                }
                ss += s.x * s.x; ss += s.y * s.y; ss += s.z * s.z; ss += s.w * s.w;
            }
            lpr[p] = log_p[jc];
            // identical source shape to the previously verified kernels:
            float o = ((dim_over_ell2 + ss) + laplace[jc]) - w * log_p[jc];
            if (!act) o = __int_as_float(0x7F800000);   // +inf: never selected
            objr[p] = o;
            const unsigned long long pk = pack_min(o, (unsigned)j);
            if (pk < lbest) lbest = pk;
        }
        post_slot(slots, block_min_reduce(lbest, red_scratch), 0);
    }
    __syncthreads();   // LDS tiers fully populated before the step loop

    // -------- steps 1..m-1: 2 barriers per step ------------------------------
    // gather_min (1 barrier) -> compute (pivot read direct from global) ->
    // lane0s->scratch (1 barrier) -> thread0 block-min + post.
    for (int t = 1; t < m; ++t) {
        gather_min(slots + (size_t)((t - 1) & 1) * GRID, t - 1, &gmin_sh);
        const int pidx = (int)(gmin_sh & 0xFFFFFull);
        if (blockIdx.x == 0 && threadIdx.x == 0) out[t - 1] = pidx;
        const size_t pb = (size_t)pidx * V;

        // OUTER-v / INNER-p (round-9 win): pivot read ONCE per v. Round-11:
        // pivot comes straight from global (L1-broadcast after first touch)
        // instead of via a serial global->LDS relay. Per-accumulator FP order
        // (v ascending, x/y/z/w) unchanged => bit-identical results.
        float r2a[PPT], c1a[PPT], c2a[PPT], dssa[PPT];
        #pragma unroll
        for (int p = 0; p < PPT; ++p) {
            r2a[p] = 0.0f; c1a[p] = 0.0f; c2a[p] = 0.0f; dssa[p] = 0.0f;
        }

        #pragma unroll
        for (int v = 0; v < V; ++v) {
            const float4 xp = X4[pb + v];
            const float4 sp = S4[pb + v];
            #pragma unroll
            for (int p = 0; p < PPT; ++p) {
                float4 xv, sv;
                if (p == 0)      { xv = xr0[v]; sv = s_ldsT[v][threadIdx.x]; }
                else if (p == 1) { xv = xr1[v]; sv = s_ldsT[v][BLOCK + threadIdx.x]; }
                else if (p == 2) {
                    xv.x = from_agpr(ax2[4 * v + 0]); xv.y = from_agpr(ax2[4 * v + 1]);
                    xv.z = from_agpr(ax2[4 * v + 2]); xv.w = from_agpr(ax2[4 * v + 3]);
                    sv.x = from_agpr(as2[4 * v + 0]); sv.y = from_agpr(as2[4 * v + 1]);
                    sv.z = from_agpr(as2[4 * v + 2]); sv.w = from_agpr(as2[4 * v + 3]);
                } else {
                    xv.x = from_agpr(ax3[4 * v + 0]); xv.y = from_agpr(ax3[4 * v + 1]);
                    xv.z = from_agpr(ax3[4 * v + 2]); xv.w = from_agpr(ax3[4 * v + 3]);
                    if (v < V3) sv = s_lds3[v][threadIdx.x];
                    else {
                        const int b = (v - V3) * 4;
                        sv.x = from_agpr(as3[b + 0]); sv.y = from_agpr(as3[b + 1]);
                        sv.z = from_agpr(as3[b + 2]); sv.w = from_agpr(as3[b + 3]);
                    }
                }
                float d;
                d = xp.x - xv.x; r2a[p] += d * d; c1a[p] += d * sp.x; c2a[p] += sv.x * d; dssa[p] += sv.x * sp.x;
                d = xp.y - xv.y; r2a[p] += d * d; c1a[p] += d * sp.y; c2a[p] += sv.y * d; dssa[p] += sv.y * sp.y;
                d = xp.z - xv.z; r2a[p] += d * d; c1a[p] += d * sp.z; c2a[p] += sv.z * d; dssa[p] += sv.z * sp.z;
                d = xp.w - xv.w; r2a[p] += d * d; c1a[p] += d * sp.w; c2a[p] += sv.w * d; dssa[p] += sv.w * sp.w;
            }
        }

        unsigned long long lbest = ~0ULL;
        #pragma unroll
        for (int p = 0; p < PPT; ++p) {
            const float r2 = r2a[p];
            const float q   = 1.0f + r2 * inv_ell2;
            const float qi  = 1.0f / q;
            const float sq  = sqrtf(qi);        // q^-0.5
            const float g   = qi * sq;          // q^-1.5
            const float q25 = qi * qi * sq;     // q^-2.5
            const float cross = (c1a[p] - c2a[p]) * inv_ell2;
            const float k = ((dim_over_ell2 * g - 3.0f * r2 * inv2 * q25)
                             + cross * g) + dssa[p] * sq;
            // +inf rows stay +inf (their loads were clamped to a real row => k finite)
            const float o = objr[p] + (2.0f * k - w * lpr[p]);
            objr[p] = o;
            const unsigned long long pk = pack_min(o, (unsigned)(tid + p * T));
            if (pk < lbest) lbest = pk;
        }

        #pragma unroll
        for (int off = 32; off >= 1; off >>= 1) {
            unsigned long long o = shfl_down_u64(lbest, off);
            lbest = (o < lbest) ? o : lbest;
        }
        if (lane == 0) red_scratch[wave] = lbest;
        __syncthreads();
        if (threadIdx.x == 0) {
            unsigned long long r = red_scratch[0];
            #pragma unroll
            for (int i = 1; i < (BLOCK / 64); ++i) {
                unsigned long long o = red_scratch[i];
                r = (o < r) ? o : r;
            }
            post_slot(slots, r, t);
        }
    }

    // -------- final argmin -> out[m-1] ----------------------------------------
    {
        gather_min(slots + (size_t)((m - 1) & 1) * GRID, m - 1, &gmin_sh);
        if (blockIdx.x == 0 && threadIdx.x == 0)
            out[m - 1] = (int)(gmin_sh & 0xFFFFFull);
    }
}

extern "C" void kernel_launch(void* const* d_in, const int* in_sizes, int n_in,
                              void* d_out, int out_size, void* d_ws, size_t ws_size,
                              hipStream_t stream) {
    const float* x        = (const float*)d_in[0];
    const float* log_p    = (const float*)d_in[1];
    const float* score_p  = (const float*)d_in[2];
    const float* laplace  = (const float*)d_in[3];
    const float* ls_ptr   = (const float*)d_in[4];

    int* out = (int*)d_out;
    int N = in_sizes[1];            // log_p has N elements
    int m = out_size;

    unsigned long long* slots = (unsigned long long*)d_ws;  // 2*GRID u64 = 4 KB

    // Single deterministic path: plain launch, identical on every call
    // (correctness call, graph capture, tripwire). 152 KB LDS => exactly
    // 1 block/CU => 256 blocks on 256 CUs are structurally co-resident.
    stein_thin_persist<<<dim3(GRID), dim3(BLOCK), 0, stream>>>(
        x, log_p, score_p, laplace, ls_ptr, out, slots, N, m);
}